// Round 19
// baseline (110.408 us; speedup 1.0000x reference)
//
#include <hip/hip_runtime.h>
#include <hip/hip_bf16.h>

// out[n,f] = weights[n] * ( x[n,:] . Wsum[f,:] + bsum[f] )
// Wsum = sum_e W[e], bsum = sum_e b[e]  (expert sum commutes with Linear).
// Wsum stored fragment-major ("Bfrag", R6) -> dense lane-consecutive B streams.
// R11/R13: producer-consumer wave specialization, 2 tiles/block, LDS dbuf.
// R16: depth-3 B prefetch with per-slice sched_barrier(0) pinning (40.7us champ).
// R17: 16-wave (8 compute + 8 stager) -- DIED of register starvation:
//      __launch_bounds__(1024) defaulted the VGPR cap to 64 < the ~84 the kloop
//      needs -> scratch spills (WRITE 274MB, FETCH 97MB, 110us).
// R18: identical, but __launch_bounds__(1024, 4): 4 waves/EU -> VGPR cap 128,
//      matching the real residency (16 waves / 4 SIMDs, 1 block/CU by LDS).

#define N_TOK 32768
#define DIM   512
#define NEXP  8
#define BM    64            // tokens per tile
#define TILES 2             // tiles per block

typedef __attribute__((ext_vector_type(8))) short  bf16x8;
typedef __attribute__((ext_vector_type(4))) float  f32x4;

__device__ __forceinline__ unsigned int pk2bf(float a, float b) {
    unsigned ua = __float_as_uint(a), ub = __float_as_uint(b);
    ua = (ua + 0x7FFFu + ((ua >> 16) & 1u)) >> 16;   // RNE to bf16
    ub = (ub + 0x7FFFu + ((ub >> 16) & 1u)) >> 16;
    return ua | (ub << 16);
}

// ---------------- prep: Bfrag (bf16, fragment-major) + bsum (f32) ---- (proven) ----
__global__ __launch_bounds__(64) void moe_prep(const float* __restrict__ W,
                                               const float* __restrict__ b,
                                               unsigned short* __restrict__ Bfrag,
                                               float* __restrict__ bsum) {
    const int g = blockIdx.x * 64 + threadIdx.x;     // 0..32767
    const int f = g >> 6;
    const int q = g & 63;
    const float* src = W + (size_t)f * DIM + q * 8;
    float s0 = 0, s1 = 0, s2 = 0, s3 = 0, s4 = 0, s5 = 0, s6 = 0, s7 = 0;
#pragma unroll
    for (int e = 0; e < NEXP; ++e) {
        float4 u0 = *(const float4*)(src + (size_t)e * DIM * DIM);
        float4 u1 = *(const float4*)(src + (size_t)e * DIM * DIM + 4);
        s0 += u0.x; s1 += u0.y; s2 += u0.z; s3 += u0.w;
        s4 += u1.x; s5 += u1.y; s6 += u1.z; s7 += u1.w;
    }
    uint4 v;
    v.x = pk2bf(s0, s1); v.y = pk2bf(s2, s3);
    v.z = pk2bf(s4, s5); v.w = pk2bf(s6, s7);

    const int F  = f >> 6, j = (f >> 4) & 3, lr = f & 15;
    const int sl = q >> 2, lg = q & 3;
    const int idx16 = ((F * 4 + j) * 16 + sl) * 64 + (lg * 16 + lr);
    *(uint4*)(Bfrag + (size_t)idx16 * 8) = v;

    if (g < DIM / 4) {
        float4 bs = make_float4(0.f, 0.f, 0.f, 0.f);
#pragma unroll
        for (int e = 0; e < NEXP; ++e) {
            float4 u = *(const float4*)(b + e * DIM + g * 4);
            bs.x += u.x; bs.y += u.y; bs.z += u.z; bs.w += u.w;
        }
        *(float4*)(bsum + g * 4) = bs;
    }
}

// ---- one granule: 8 f32 -> 16B bf16, XOR-swizzled LDS write (proven pair) ----
__device__ __forceinline__ void stage_granule(const float* __restrict__ srcrow,
                                              unsigned char* __restrict__ dstrow,
                                              int g, int row) {
    float4 u0 = *(const float4*)(srcrow + g * 8);
    float4 u1 = *(const float4*)(srcrow + g * 8 + 4);
    const int sg = (g & ~7) | ((g ^ row) & 7);
    uint4 v;
    v.x = pk2bf(u0.x, u0.y); v.y = pk2bf(u0.z, u0.w);
    v.z = pk2bf(u1.x, u1.y); v.w = pk2bf(u1.z, u1.w);
    *(uint4*)(dstrow + sg * 16) = v;
}

// ---------------- main GEMM: 16 waves (8 compute + 8 stage), 2 tiles ----------------
// Grid 256 (1 block/CU via 128KB LDS). w0-7 compute (wave w owns features
// [w*64,(w+1)*64) of 64 tokens), w8-15 stage tile1 during kloop(0).
__global__ __launch_bounds__(1024, 4) void moe_gemm(const float* __restrict__ x,
                                                    const float* __restrict__ wts,
                                                    const unsigned short* __restrict__ Bf,
                                                    const float* __restrict__ bsum,
                                                    float* __restrict__ out) {
    __shared__ __align__(16) unsigned char ldsA[2][BM * DIM * 2];   // 2 x 64 KB

    const int tid  = threadIdx.x;
    const int lane = tid & 63;
    const int w    = tid >> 6;       // 0..15
    const bool stager = (w >= 8);
    const int lr   = lane & 15;
    const int lg   = lane >> 4;
    const int blk  = blockIdx.x;
    const int f0   = w * 64;         // compute waves only

    // ---- front: stage tile0 with ALL 16 waves. 64x64 = 4096 granules over 1024
    //      threads: gl = u*1024 + tid, u=0..3 (exact, no guard).
    {
        const float* src0 = x + (size_t)(blk * TILES) * BM * DIM;
#pragma unroll
        for (int u = 0; u < 4; ++u) {
            const int gl = u * 1024 + tid;
            const int row = gl >> 6;
            const int g   = gl & 63;
            stage_granule(src0 + (size_t)row * DIM, ldsA[0] + row * 1024, g, row);
        }
    }
    __syncthreads();                  // bar1: buf0 ready

    // ---- stager geometry for tile1: st=tid-512 (0..511) -> row st>>3 (0..63), slot st&7
    const int st   = tid - 512;
    const int arow = (st >> 3) & 63;
    const int as0  = st & 7;

    // ---- compute lambdas (R16-proven)
    const bf16x8* bfr = (const bf16x8*)Bf + (size_t)w * 4096 + lane;   // + j*1024 + s*64

    f32x4 acc[4][4];
    bf16x8 b0[4], b1[4], b2[4], af[4];

    auto loadB = [&](int s, bf16x8 (&bb)[4]) {
#pragma unroll
        for (int j = 0; j < 4; ++j)
            bb[j] = bfr[j * 1024 + s * 64];
    };
    auto sliceA = [&](int buf, int s) {
#pragma unroll
        for (int i = 0; i < 4; ++i) {
            const int row = i * 16 + lr;
            const int gsl = s * 4 + lg;
            const int sw  = (gsl & ~7) | ((gsl ^ row) & 7);
            af[i] = *(const bf16x8*)(ldsA[buf] + row * 1024 + sw * 16);
        }
    };
    auto mf = [&](bf16x8 (&bb)[4]) {
#pragma unroll
        for (int j = 0; j < 4; ++j)
#pragma unroll
            for (int i = 0; i < 4; ++i)
                acc[j][i] = __builtin_amdgcn_mfma_f32_16x16x32_bf16(bb[j], af[i], acc[j][i], 0, 0, 0);
    };
    // depth-3 rotation (R16-proven): slice s uses b[s%3]; reload s+3 after MFMAs;
    // sched_barrier(0) pins issue order.
    auto kloop = [&](int buf) {
#pragma unroll
        for (int j = 0; j < 4; ++j)
#pragma unroll
            for (int i = 0; i < 4; ++i)
                acc[j][i] = f32x4{0.f, 0.f, 0.f, 0.f};
        loadB(0, b0); loadB(1, b1); loadB(2, b2);
#define KSTEP(s, BSET)                                        \
        { sliceA(buf, s); mf(BSET);                           \
          if ((s) + 3 < 16) loadB((s) + 3, BSET);             \
          __builtin_amdgcn_sched_barrier(0); }
        KSTEP(0,  b0) KSTEP(1,  b1) KSTEP(2,  b2)
        KSTEP(3,  b0) KSTEP(4,  b1) KSTEP(5,  b2)
        KSTEP(6,  b0) KSTEP(7,  b1) KSTEP(8,  b2)
        KSTEP(9,  b0) KSTEP(10, b1) KSTEP(11, b2)
        KSTEP(12, b0) KSTEP(13, b1) KSTEP(14, b2)
        KSTEP(15, b0)
#undef KSTEP
    };
    auto epilogue = [&](int tile) {
        const int m0 = (blk * TILES + tile) * BM;
        f32x4 bs4[4];
#pragma unroll
        for (int j = 0; j < 4; ++j)
            bs4[j] = *(const f32x4*)(bsum + f0 + j * 16 + lg * 4);
#pragma unroll
        for (int i = 0; i < 4; ++i) {
            const int row = m0 + i * 16 + lr;
            const float wt = wts[row];
#pragma unroll
            for (int j = 0; j < 4; ++j) {
                f32x4 v;
                v[0] = wt * (acc[j][i][0] + bs4[j][0]);
                v[1] = wt * (acc[j][i][1] + bs4[j][1]);
                v[2] = wt * (acc[j][i][2] + bs4[j][2]);
                v[3] = wt * (acc[j][i][3] + bs4[j][3]);
                *(f32x4*)(out + (size_t)row * DIM + f0 + j * 16 + lg * 4) = v;
            }
        }
    };

    // ================= schedule (R11-proven) =================
    if (stager) {
        // stage tile1 WHILE compute runs tile0: 8 granules/thread, 8 waves wide
        const float* srcrow = x + (size_t)((blk * TILES + 1) * BM + arow) * DIM;
        unsigned char* dstrow = ldsA[1] + arow * 1024;
#pragma unroll
        for (int u = 0; u < 8; ++u)
            stage_granule(srcrow, dstrow, as0 + u * 8, arow);
    } else {
        kloop(0);                     // tile0 compute (A from buf0, B from L2)
    }
    __syncthreads();                  // bar2: buf1 ready

    if (!stager) {
        epilogue(0);                  // tile0 stores issue; drain under tile1 kloop
        kloop(1);                     // tile1 compute
        epilogue(1);                  // tail drain
    }
}

extern "C" void kernel_launch(void* const* d_in, const int* in_sizes, int n_in,
                              void* d_out, int out_size, void* d_ws, size_t ws_size,
                              hipStream_t stream) {
    const float* x   = (const float*)d_in[0];   // [N, D]
    const float* wts = (const float*)d_in[1];   // [N, 1]
    const float* W   = (const float*)d_in[2];   // [E, D, D]
    const float* b   = (const float*)d_in[3];   // [E, D]
    float* out       = (float*)d_out;           // [N, D]

    unsigned short* Bfrag = (unsigned short*)d_ws;                    // 512 KB bf16
    float*          bsum  = (float*)((char*)d_ws + DIM * DIM * 2);    // 2 KB f32

    moe_prep<<<dim3((DIM * DIM / 8) / 64), dim3(64), 0, stream>>>(W, b, Bfrag, bsum);

    moe_gemm<<<dim3(N_TOK / (BM * TILES)), dim3(1024), 0, stream>>>(x, wts, Bfrag, bsum, out);
}

// Round 20
// 40.679 us; speedup vs baseline: 2.7141x; 2.7141x over previous
//
#include <hip/hip_runtime.h>
#include <hip/hip_bf16.h>

// out[n,f] = weights[n] * ( x[n,:] . Wsum[f,:] + bsum[f] )
// Wsum = sum_e W[e], bsum = sum_e b[e]  (expert sum commutes with Linear).
// Wsum stored fragment-major ("Bfrag", R6) -> dense lane-consecutive B streams.
// R16 champion: 12-wave producer-consumer, depth-3 pinned B prefetch (40.7us).
// R19: NO dedicated stagers -- 8-wave block; tile1 staging is folded INTO
// kloop(0): KSTEP 0-7 issue one granule-pair LOAD each (T14 issue-early),
// KSTEP 8-15 convert+ds_write (write-late). sched_barrier(0) per KSTEP (R16-
// proven) pins issue order. 512 thr + 128KB LDS -> 1 block/CU -> 2 waves/SIMD
// -> 256-VGPR cap: the pipeline finally has register room (R5/R10/R17/R18's
// attempts all died of the 64/84-VGPR wall).

#define N_TOK 32768
#define DIM   512
#define NEXP  8
#define BM    64            // tokens per tile
#define TILES 2             // tiles per block

typedef __attribute__((ext_vector_type(8))) short  bf16x8;
typedef __attribute__((ext_vector_type(4))) float  f32x4;

__device__ __forceinline__ unsigned int pk2bf(float a, float b) {
    unsigned ua = __float_as_uint(a), ub = __float_as_uint(b);
    ua = (ua + 0x7FFFu + ((ua >> 16) & 1u)) >> 16;   // RNE to bf16
    ub = (ub + 0x7FFFu + ((ub >> 16) & 1u)) >> 16;
    return ua | (ub << 16);
}

// ---------------- prep: Bfrag (bf16, fragment-major) + bsum (f32) ---- (proven) ----
__global__ __launch_bounds__(64) void moe_prep(const float* __restrict__ W,
                                               const float* __restrict__ b,
                                               unsigned short* __restrict__ Bfrag,
                                               float* __restrict__ bsum) {
    const int g = blockIdx.x * 64 + threadIdx.x;     // 0..32767
    const int f = g >> 6;
    const int q = g & 63;
    const float* src = W + (size_t)f * DIM + q * 8;
    float s0 = 0, s1 = 0, s2 = 0, s3 = 0, s4 = 0, s5 = 0, s6 = 0, s7 = 0;
#pragma unroll
    for (int e = 0; e < NEXP; ++e) {
        float4 u0 = *(const float4*)(src + (size_t)e * DIM * DIM);
        float4 u1 = *(const float4*)(src + (size_t)e * DIM * DIM + 4);
        s0 += u0.x; s1 += u0.y; s2 += u0.z; s3 += u0.w;
        s4 += u1.x; s5 += u1.y; s6 += u1.z; s7 += u1.w;
    }
    uint4 v;
    v.x = pk2bf(s0, s1); v.y = pk2bf(s2, s3);
    v.z = pk2bf(s4, s5); v.w = pk2bf(s6, s7);

    const int F  = f >> 6, j = (f >> 4) & 3, lr = f & 15;
    const int sl = q >> 2, lg = q & 3;
    const int idx16 = ((F * 4 + j) * 16 + sl) * 64 + (lg * 16 + lr);
    *(uint4*)(Bfrag + (size_t)idx16 * 8) = v;

    if (g < DIM / 4) {
        float4 bs = make_float4(0.f, 0.f, 0.f, 0.f);
#pragma unroll
        for (int e = 0; e < NEXP; ++e) {
            float4 u = *(const float4*)(b + e * DIM + g * 4);
            bs.x += u.x; bs.y += u.y; bs.z += u.z; bs.w += u.w;
        }
        *(float4*)(bsum + g * 4) = bs;
    }
}

// ---- one granule: 8 f32 -> 16B bf16, XOR-swizzled LDS write (proven pair) ----
__device__ __forceinline__ void stage_granule(const float* __restrict__ srcrow,
                                              unsigned char* __restrict__ dstrow,
                                              int g, int row) {
    float4 u0 = *(const float4*)(srcrow + g * 8);
    float4 u1 = *(const float4*)(srcrow + g * 8 + 4);
    const int sg = (g & ~7) | ((g ^ row) & 7);
    uint4 v;
    v.x = pk2bf(u0.x, u0.y); v.y = pk2bf(u0.z, u0.w);
    v.z = pk2bf(u1.x, u1.y); v.w = pk2bf(u1.z, u1.w);
    *(uint4*)(dstrow + sg * 16) = v;
}

// ---------------- main GEMM: 8 waves, staging folded into kloop0 ----------------
// Grid 256 (1 block/CU via 128KB LDS). Wave w owns features [w*64,(w+1)*64).
__global__ __launch_bounds__(512, 2) void moe_gemm(const float* __restrict__ x,
                                                   const float* __restrict__ wts,
                                                   const unsigned short* __restrict__ Bf,
                                                   const float* __restrict__ bsum,
                                                   float* __restrict__ out) {
    __shared__ __align__(16) unsigned char ldsA[2][BM * DIM * 2];   // 2 x 64 KB

    const int tid  = threadIdx.x;
    const int lane = tid & 63;
    const int w    = tid >> 6;       // 0..7
    const int lr   = lane & 15;
    const int lg   = lane >> 4;
    const int blk  = blockIdx.x;
    const int f0   = w * 64;

    // ---- staging geometry (both tiles): row = tid>>3 (0..63), slot s0 = tid&7,
    //      granules g = s0 + u*8, u = 0..7 (8 granules/thread, 512 thr -> 64x64).
    const int arow = tid >> 3;
    const int as0  = tid & 7;
    unsigned char* dst0 = ldsA[0] + arow * 1024;
    unsigned char* dst1 = ldsA[1] + arow * 1024;

    // ---- front: stage tile0 with all 8 waves
    {
        const float* srcrow = x + (size_t)(blk * TILES * BM + arow) * DIM;
#pragma unroll
        for (int u = 0; u < 8; ++u)
            stage_granule(srcrow, dst0, as0 + u * 8, arow);
    }
    __syncthreads();                  // bar1: buf0 ready

    // ---- compute lambdas (R16-proven)
    const bf16x8* bfr = (const bf16x8*)Bf + (size_t)w * 4096 + lane;   // + j*1024 + s*64

    f32x4 acc[4][4];
    bf16x8 b0[4], b1[4], b2[4], af[4];

    auto loadB = [&](int s, bf16x8 (&bb)[4]) {
#pragma unroll
        for (int j = 0; j < 4; ++j)
            bb[j] = bfr[j * 1024 + s * 64];
    };
    auto sliceA = [&](int buf, int s) {
#pragma unroll
        for (int i = 0; i < 4; ++i) {
            const int row = i * 16 + lr;
            const int gsl = s * 4 + lg;
            const int sw  = (gsl & ~7) | ((gsl ^ row) & 7);
            af[i] = *(const bf16x8*)(ldsA[buf] + row * 1024 + sw * 16);
        }
    };
    auto mf = [&](bf16x8 (&bb)[4]) {
#pragma unroll
        for (int j = 0; j < 4; ++j)
#pragma unroll
            for (int i = 0; i < 4; ++i)
                acc[j][i] = __builtin_amdgcn_mfma_f32_16x16x32_bf16(bb[j], af[i], acc[j][i], 0, 0, 0);
    };
    auto zacc = [&]() {
#pragma unroll
        for (int j = 0; j < 4; ++j)
#pragma unroll
            for (int i = 0; i < 4; ++i)
                acc[j][i] = f32x4{0.f, 0.f, 0.f, 0.f};
    };
    auto epilogue = [&](int tile) {
        const int m0 = (blk * TILES + tile) * BM;
        f32x4 bs4[4];
#pragma unroll
        for (int j = 0; j < 4; ++j)
            bs4[j] = *(const f32x4*)(bsum + f0 + j * 16 + lg * 4);
#pragma unroll
        for (int i = 0; i < 4; ++i) {
            const int row = m0 + i * 16 + lr;
            const float wt = wts[row];
#pragma unroll
            for (int j = 0; j < 4; ++j) {
                f32x4 v;
                v[0] = wt * (acc[j][i][0] + bs4[j][0]);
                v[1] = wt * (acc[j][i][1] + bs4[j][1]);
                v[2] = wt * (acc[j][i][2] + bs4[j][2]);
                v[3] = wt * (acc[j][i][3] + bs4[j][3]);
                *(f32x4*)(out + (size_t)row * DIM + f0 + j * 16 + lg * 4) = v;
            }
        }
    };

    // ---- in-flight tile1 staging registers (static-indexed via macro literals)
    float4 sA[8], sB[8];
    const float* srcrow1 = x + (size_t)((blk * TILES + 1) * BM + arow) * DIM;

    // ================= kloop(0) with folded tile1 staging =================
    zacc();
    loadB(0, b0); loadB(1, b1); loadB(2, b2);
    // KSTEP s: MFMA slice s (B set s%3), reload B s+3, and:
    //   s in [0,8): ISSUE granule-pair load u=s   (fire early, drains under MFMAs)
    //   s in [8,16): convert+ds_write u=s-8       (write late; bar2 fences)
#define STLOAD(u)                                                          \
        { const float* p = srcrow1 + (as0 + (u) * 8) * 8;                  \
          sA[u] = *(const float4*)p; sB[u] = *(const float4*)(p + 4); }
#define STWRITE(u)                                                         \
        { const int g  = as0 + (u) * 8;                                    \
          const int sg = (g & ~7) | ((g ^ arow) & 7);                      \
          uint4 v;                                                         \
          v.x = pk2bf(sA[u].x, sA[u].y); v.y = pk2bf(sA[u].z, sA[u].w);    \
          v.z = pk2bf(sB[u].x, sB[u].y); v.w = pk2bf(sB[u].z, sB[u].w);    \
          *(uint4*)(dst1 + sg * 16) = v; }
#define KSTEP0(s, BSET)                                                    \
        { sliceA(0, s); mf(BSET);                                          \
          if ((s) + 3 < 16) loadB((s) + 3, BSET);                          \
          if ((s) < 8) { STLOAD(s) } else { STWRITE((s) - 8) }             \
          __builtin_amdgcn_sched_barrier(0); }
    KSTEP0(0,  b0) KSTEP0(1,  b1) KSTEP0(2,  b2)
    KSTEP0(3,  b0) KSTEP0(4,  b1) KSTEP0(5,  b2)
    KSTEP0(6,  b0) KSTEP0(7,  b1) KSTEP0(8,  b2)
    KSTEP0(9,  b0) KSTEP0(10, b1) KSTEP0(11, b2)
    KSTEP0(12, b0) KSTEP0(13, b1) KSTEP0(14, b2)
    KSTEP0(15, b0)
#undef KSTEP0
#undef STWRITE
#undef STLOAD
    __syncthreads();                  // bar2: buf1 ready (ds_writes fenced)

    epilogue(0);                      // tile0 stores issue; drain under kloop1

    // ================= kloop(1), plain R16 =================
    zacc();
    loadB(0, b0); loadB(1, b1); loadB(2, b2);
#define KSTEP(s, BSET)                                        \
        { sliceA(1, s); mf(BSET);                             \
          if ((s) + 3 < 16) loadB((s) + 3, BSET);             \
          __builtin_amdgcn_sched_barrier(0); }
    KSTEP(0,  b0) KSTEP(1,  b1) KSTEP(2,  b2)
    KSTEP(3,  b0) KSTEP(4,  b1) KSTEP(5,  b2)
    KSTEP(6,  b0) KSTEP(7,  b1) KSTEP(8,  b2)
    KSTEP(9,  b0) KSTEP(10, b1) KSTEP(11, b2)
    KSTEP(12, b0) KSTEP(13, b1) KSTEP(14, b2)
    KSTEP(15, b0)
#undef KSTEP

    epilogue(1);                      // tail drain
}

extern "C" void kernel_launch(void* const* d_in, const int* in_sizes, int n_in,
                              void* d_out, int out_size, void* d_ws, size_t ws_size,
                              hipStream_t stream) {
    const float* x   = (const float*)d_in[0];   // [N, D]
    const float* wts = (const float*)d_in[1];   // [N, 1]
    const float* W   = (const float*)d_in[2];   // [E, D, D]
    const float* b   = (const float*)d_in[3];   // [E, D]
    float* out       = (float*)d_out;           // [N, D]

    unsigned short* Bfrag = (unsigned short*)d_ws;                    // 512 KB bf16
    float*          bsum  = (float*)((char*)d_ws + DIM * DIM * 2);    // 2 KB f32

    moe_prep<<<dim3((DIM * DIM / 8) / 64), dim3(64), 0, stream>>>(W, b, Bfrag, bsum);

    moe_gemm<<<dim3(N_TOK / (BM * TILES)), dim3(512), 0, stream>>>(x, wts, Bfrag, bsum, out);
}

// Round 21
// 40.607 us; speedup vs baseline: 2.7189x; 1.0018x over previous
//
#include <hip/hip_runtime.h>
#include <hip/hip_bf16.h>

// out[n,f] = weights[n] * ( x[n,:] . Wsum[f,:] + bsum[f] )
// Wsum = sum_e W[e], bsum = sum_e b[e]  (expert sum commutes with Linear).
// Wsum stored fragment-major ("Bfrag", R6) -> dense lane-consecutive B streams.
// R16/R19 champion (40.7us): 16-step depth-3 pinned kloop, staging folded in.
// R20: HALF-FRONT -- stage only k[0,256) of tile0 before bar1 (slices 0-7);
// tile0's k[256,512) is loaded at kloop steps 0-3 and written at steps 4-7
// (disjoint LDS region, slices 8-15), bar2 mid-kloop makes it visible before
// step 8; steps 8-15 fold tile1 loads (R19-proven). Front read exposure halves.

#define N_TOK 32768
#define DIM   512
#define NEXP  8
#define BM    64            // tokens per tile
#define TILES 2             // tiles per block

typedef __attribute__((ext_vector_type(8))) short  bf16x8;
typedef __attribute__((ext_vector_type(4))) float  f32x4;

__device__ __forceinline__ unsigned int pk2bf(float a, float b) {
    unsigned ua = __float_as_uint(a), ub = __float_as_uint(b);
    ua = (ua + 0x7FFFu + ((ua >> 16) & 1u)) >> 16;   // RNE to bf16
    ub = (ub + 0x7FFFu + ((ub >> 16) & 1u)) >> 16;
    return ua | (ub << 16);
}

// ---------------- prep: Bfrag (bf16, fragment-major) + bsum (f32) ---- (proven) ----
__global__ __launch_bounds__(64) void moe_prep(const float* __restrict__ W,
                                               const float* __restrict__ b,
                                               unsigned short* __restrict__ Bfrag,
                                               float* __restrict__ bsum) {
    const int g = blockIdx.x * 64 + threadIdx.x;     // 0..32767
    const int f = g >> 6;
    const int q = g & 63;
    const float* src = W + (size_t)f * DIM + q * 8;
    float s0 = 0, s1 = 0, s2 = 0, s3 = 0, s4 = 0, s5 = 0, s6 = 0, s7 = 0;
#pragma unroll
    for (int e = 0; e < NEXP; ++e) {
        float4 u0 = *(const float4*)(src + (size_t)e * DIM * DIM);
        float4 u1 = *(const float4*)(src + (size_t)e * DIM * DIM + 4);
        s0 += u0.x; s1 += u0.y; s2 += u0.z; s3 += u0.w;
        s4 += u1.x; s5 += u1.y; s6 += u1.z; s7 += u1.w;
    }
    uint4 v;
    v.x = pk2bf(s0, s1); v.y = pk2bf(s2, s3);
    v.z = pk2bf(s4, s5); v.w = pk2bf(s6, s7);

    const int F  = f >> 6, j = (f >> 4) & 3, lr = f & 15;
    const int sl = q >> 2, lg = q & 3;
    const int idx16 = ((F * 4 + j) * 16 + sl) * 64 + (lg * 16 + lr);
    *(uint4*)(Bfrag + (size_t)idx16 * 8) = v;

    if (g < DIM / 4) {
        float4 bs = make_float4(0.f, 0.f, 0.f, 0.f);
#pragma unroll
        for (int e = 0; e < NEXP; ++e) {
            float4 u = *(const float4*)(b + e * DIM + g * 4);
            bs.x += u.x; bs.y += u.y; bs.z += u.z; bs.w += u.w;
        }
        *(float4*)(bsum + g * 4) = bs;
    }
}

// ---- one granule: 8 f32 -> 16B bf16, XOR-swizzled LDS write (proven pair) ----
__device__ __forceinline__ void stage_granule(const float* __restrict__ srcrow,
                                              unsigned char* __restrict__ dstrow,
                                              int g, int row) {
    float4 u0 = *(const float4*)(srcrow + g * 8);
    float4 u1 = *(const float4*)(srcrow + g * 8 + 4);
    const int sg = (g & ~7) | ((g ^ row) & 7);
    uint4 v;
    v.x = pk2bf(u0.x, u0.y); v.y = pk2bf(u0.z, u0.w);
    v.z = pk2bf(u1.x, u1.y); v.w = pk2bf(u1.z, u1.w);
    *(uint4*)(dstrow + sg * 16) = v;
}

// ---------------- main GEMM: 8 waves, half-front, staged-in-kloop ----------------
// Grid 256 (1 block/CU via 128KB LDS). Wave w owns features [w*64,(w+1)*64).
__global__ __launch_bounds__(512, 2) void moe_gemm(const float* __restrict__ x,
                                                   const float* __restrict__ wts,
                                                   const unsigned short* __restrict__ Bf,
                                                   const float* __restrict__ bsum,
                                                   float* __restrict__ out) {
    __shared__ __align__(16) unsigned char ldsA[2][BM * DIM * 2];   // 2 x 64 KB

    const int tid  = threadIdx.x;
    const int lane = tid & 63;
    const int w    = tid >> 6;       // 0..7
    const int lr   = lane & 15;
    const int lg   = lane >> 4;
    const int blk  = blockIdx.x;
    const int f0   = w * 64;

    // ---- staging geometry: row = tid>>3 (0..63), slot s0 = tid&7,
    //      granule g = s0 + u*8; g in [0,32) = slices 0-7, [32,64) = slices 8-15.
    const int arow = tid >> 3;
    const int as0  = tid & 7;
    unsigned char* dst0 = ldsA[0] + arow * 1024;
    unsigned char* dst1 = ldsA[1] + arow * 1024;
    const float* srcrow0 = x + (size_t)(blk * TILES * BM + arow) * DIM;
    const float* srcrow1 = x + (size_t)((blk * TILES + 1) * BM + arow) * DIM;

    // ---- half-front: stage tile0 granules u=0..3 (k columns 0..255, slices 0-7)
#pragma unroll
    for (int u = 0; u < 4; ++u)
        stage_granule(srcrow0, dst0, as0 + u * 8, arow);
    __syncthreads();                  // bar1: buf0 slices 0-7 ready

    // ---- compute lambdas (R16-proven)
    const bf16x8* bfr = (const bf16x8*)Bf + (size_t)w * 4096 + lane;   // + j*1024 + s*64

    f32x4 acc[4][4];
    bf16x8 b0[4], b1[4], b2[4], af[4];

    auto loadB = [&](int s, bf16x8 (&bb)[4]) {
#pragma unroll
        for (int j = 0; j < 4; ++j)
            bb[j] = bfr[j * 1024 + s * 64];
    };
    auto sliceA = [&](int buf, int s) {
#pragma unroll
        for (int i = 0; i < 4; ++i) {
            const int row = i * 16 + lr;
            const int gsl = s * 4 + lg;
            const int sw  = (gsl & ~7) | ((gsl ^ row) & 7);
            af[i] = *(const bf16x8*)(ldsA[buf] + row * 1024 + sw * 16);
        }
    };
    auto mf = [&](bf16x8 (&bb)[4]) {
#pragma unroll
        for (int j = 0; j < 4; ++j)
#pragma unroll
            for (int i = 0; i < 4; ++i)
                acc[j][i] = __builtin_amdgcn_mfma_f32_16x16x32_bf16(bb[j], af[i], acc[j][i], 0, 0, 0);
    };
    auto zacc = [&]() {
#pragma unroll
        for (int j = 0; j < 4; ++j)
#pragma unroll
            for (int i = 0; i < 4; ++i)
                acc[j][i] = f32x4{0.f, 0.f, 0.f, 0.f};
    };
    auto epilogue = [&](int tile) {
        const int m0 = (blk * TILES + tile) * BM;
        f32x4 bs4[4];
#pragma unroll
        for (int j = 0; j < 4; ++j)
            bs4[j] = *(const f32x4*)(bsum + f0 + j * 16 + lg * 4);
#pragma unroll
        for (int i = 0; i < 4; ++i) {
            const int row = m0 + i * 16 + lr;
            const float wt = wts[row];
#pragma unroll
            for (int j = 0; j < 4; ++j) {
                f32x4 v;
                v[0] = wt * (acc[j][i][0] + bs4[j][0]);
                v[1] = wt * (acc[j][i][1] + bs4[j][1]);
                v[2] = wt * (acc[j][i][2] + bs4[j][2]);
                v[3] = wt * (acc[j][i][3] + bs4[j][3]);
                *(f32x4*)(out + (size_t)row * DIM + f0 + j * 16 + lg * 4) = v;
            }
        }
    };

    // ---- in-flight staging registers (static-indexed via macro literals)
    float4 tA[4], tB[4];   // tile0 second half (granules 32..63)
    float4 sA[8], sB[8];   // tile1 (granules 0..63)

    // ================= kloop(0): slices 0-15 with staged payloads =================
    zacc();
    loadB(0, b0); loadB(1, b1); loadB(2, b2);
#define T0LOAD(u)                                                          \
        { const float* p = srcrow0 + (as0 + ((u) + 4) * 8) * 8;            \
          tA[u] = *(const float4*)p; tB[u] = *(const float4*)(p + 4); }
#define T0WRITE(u)                                                         \
        { const int g  = as0 + ((u) + 4) * 8;                              \
          const int sg = (g & ~7) | ((g ^ arow) & 7);                      \
          uint4 v;                                                         \
          v.x = pk2bf(tA[u].x, tA[u].y); v.y = pk2bf(tA[u].z, tA[u].w);    \
          v.z = pk2bf(tB[u].x, tB[u].y); v.w = pk2bf(tB[u].z, tB[u].w);    \
          *(uint4*)(dst0 + sg * 16) = v; }
#define T1LOAD(u)                                                          \
        { const float* p = srcrow1 + (as0 + (u) * 8) * 8;                  \
          sA[u] = *(const float4*)p; sB[u] = *(const float4*)(p + 4); }
#define T1WRITE(u)                                                         \
        { const int g  = as0 + (u) * 8;                                    \
          const int sg = (g & ~7) | ((g ^ arow) & 7);                      \
          uint4 v;                                                         \
          v.x = pk2bf(sA[u].x, sA[u].y); v.y = pk2bf(sA[u].z, sA[u].w);    \
          v.z = pk2bf(sB[u].x, sB[u].y); v.w = pk2bf(sB[u].z, sB[u].w);    \
          *(uint4*)(dst1 + sg * 16) = v; }
#define KS(s, BSET, PAYLOAD)                                               \
        { sliceA(0, s); mf(BSET);                                          \
          if ((s) + 3 < 16) loadB((s) + 3, BSET);                          \
          PAYLOAD                                                          \
          __builtin_amdgcn_sched_barrier(0); }
    KS(0,  b0, T0LOAD(0))  KS(1,  b1, T0LOAD(1))  KS(2,  b2, T0LOAD(2))
    KS(3,  b0, T0LOAD(3))  KS(4,  b1, T0WRITE(0)) KS(5,  b2, T0WRITE(1))
    KS(6,  b0, T0WRITE(2)) KS(7,  b1, T0WRITE(3))
    __syncthreads();                  // bar2: buf0 slices 8-15 visible
    KS(8,  b2, T1LOAD(0))  KS(9,  b0, T1LOAD(1))  KS(10, b1, T1LOAD(2))
    KS(11, b2, T1LOAD(3))  KS(12, b0, T1LOAD(4))  KS(13, b1, T1LOAD(5))
    KS(14, b2, T1LOAD(6))  KS(15, b0, T1LOAD(7))
#undef KS
    T1WRITE(0) T1WRITE(1) T1WRITE(2) T1WRITE(3)
    T1WRITE(4) T1WRITE(5) T1WRITE(6) T1WRITE(7)
    __syncthreads();                  // bar3: buf1 ready
#undef T1WRITE
#undef T1LOAD
#undef T0WRITE
#undef T0LOAD

    epilogue(0);                      // tile0 stores issue; drain under kloop(1)

    // ================= kloop(1), plain R16 =================
    zacc();
    loadB(0, b0); loadB(1, b1); loadB(2, b2);
#define KSTEP(s, BSET)                                        \
        { sliceA(1, s); mf(BSET);                             \
          if ((s) + 3 < 16) loadB((s) + 3, BSET);             \
          __builtin_amdgcn_sched_barrier(0); }
    KSTEP(0,  b0) KSTEP(1,  b1) KSTEP(2,  b2)
    KSTEP(3,  b0) KSTEP(4,  b1) KSTEP(5,  b2)
    KSTEP(6,  b0) KSTEP(7,  b1) KSTEP(8,  b2)
    KSTEP(9,  b0) KSTEP(10, b1) KSTEP(11, b2)
    KSTEP(12, b0) KSTEP(13, b1) KSTEP(14, b2)
    KSTEP(15, b0)
#undef KSTEP

    epilogue(1);                      // tail drain
}

extern "C" void kernel_launch(void* const* d_in, const int* in_sizes, int n_in,
                              void* d_out, int out_size, void* d_ws, size_t ws_size,
                              hipStream_t stream) {
    const float* x   = (const float*)d_in[0];   // [N, D]
    const float* wts = (const float*)d_in[1];   // [N, 1]
    const float* W   = (const float*)d_in[2];   // [E, D, D]
    const float* b   = (const float*)d_in[3];   // [E, D]
    float* out       = (float*)d_out;           // [N, D]

    unsigned short* Bfrag = (unsigned short*)d_ws;                    // 512 KB bf16
    float*          bsum  = (float*)((char*)d_ws + DIM * DIM * 2);    // 2 KB f32

    moe_prep<<<dim3((DIM * DIM / 8) / 64), dim3(64), 0, stream>>>(W, b, Bfrag, bsum);

    moe_gemm<<<dim3(N_TOK / (BM * TILES)), dim3(512), 0, stream>>>(x, wts, Bfrag, bsum, out);
}